// Round 1
// baseline (706.916 us; speedup 1.0000x reference)
//
#include <hip/hip_runtime.h>

#define CH 256
#define KC 8192
#define KCP 8448       // padded codebook: 3 * 2816, grid.y = 3
#define NT 32768

#define TM 128         // tokens per block
#define TN 128         // codes per jt tile
#define BK 32          // channels staged per stage
#define YS 3           // code thirds (grid.y)
#define JQ (KCP / YS)  // 2816 codes per block
#define NSTG ((JQ / TN) * (CH / BK))   // 22 jt * 8 c0 = 176 stages

typedef _Float16 half4_t __attribute__((ext_vector_type(4)));
typedef _Float16 half8_t __attribute__((ext_vector_type(8)));
typedef float floatx4 __attribute__((ext_vector_type(4)));

typedef __attribute__((address_space(1))) const unsigned int guint_t;
typedef __attribute__((address_space(3))) unsigned int luint_t;

// XOR-swizzled LDS offset (halves) for row-major [row][BK] tiles, 16B chunks.
__device__ __forceinline__ int swz(int row, int chunk) {
    return row * BK + ((chunk ^ ((row >> 1) & 3)) << 3);
}

// ---------------------------------------------------------------------------
// Kernel 1 (fused prep):
//  blocks [0, KCP):   codebook row -> fp16 hi/lo + cbsq (pad rows: 0 / 3e38),
//                     zero hist, init packed keys
//  blocks [KCP, ...): split embeddings fp32 -> fp16 hi/lo (1 float4/thread)
// ---------------------------------------------------------------------------
__global__ void k_prep(const float* __restrict__ usage,
                       const float* __restrict__ ces,
                       const float* __restrict__ emb,
                       _Float16* __restrict__ cbh,
                       _Float16* __restrict__ cbl,
                       float* __restrict__ cbsq,
                       _Float16* __restrict__ eh,
                       _Float16* __restrict__ el,
                       int* __restrict__ hist,
                       unsigned long long* __restrict__ packed) {
    int b = blockIdx.x, t = threadIdx.x;
    if (b < KCP) {
        if (b < KC) {
            float uc = fmaxf(usage[b], 1e-5f);
            float v  = ces[b * CH + t];
            float cb = v / uc;
            _Float16 h = (_Float16)cb;
            cbh[b * CH + t] = h;
            cbl[b * CH + t] = (_Float16)(cb - (float)h);

            float p = cb * cb;
            #pragma unroll
            for (int off = 32; off; off >>= 1) p += __shfl_down(p, off);
            __shared__ float ps[4];
            int lane = t & 63, w = t >> 6;
            if (lane == 0) ps[w] = p;
            __syncthreads();
            if (t == 0) cbsq[b] = ps[0] + ps[1] + ps[2] + ps[3];
            if (t == 1) hist[b] = 0;
            int gid = b * CH + t;
            if (gid < NT) packed[gid] = 0xFFFFFFFFFFFFFFFFull;
        } else {
            cbh[b * CH + t] = (_Float16)0.0f;
            cbl[b * CH + t] = (_Float16)0.0f;
            if (t == 0) cbsq[b] = 3.0e38f;
        }
    } else {
        int i = (b - KCP) * 256 + t;     // float4 index
        float4 v = ((const float4*)emb)[i];
        float va[4] = {v.x, v.y, v.z, v.w};
        half4_t h, l;
        #pragma unroll
        for (int q = 0; q < 4; ++q) {
            _Float16 hh = (_Float16)va[q];
            h[q] = hh;
            l[q] = (_Float16)(va[q] - (float)hh);
        }
        ((half4_t*)eh)[i] = h;
        ((half4_t*)el)[i] = l;
    }
}

// ---------------------------------------------------------------------------
// Kernel 2: fp16-split MFMA argmin.
// DOUBLE-buffered 2x32KB LDS staged by global_load_lds (16B DMA). Stage s+1's
// 8 loads/wave are issued BEFORE computing stage s; raw s_barrier + counted
// s_waitcnt vmcnt(8) (never 0 in steady state) keeps the prefetch in flight
// across the barrier (T3+T4). Wave w DMAs array w of {Ah,Al,Bh,Bl}; lane->
// chunk assignment pre-applies the XOR swizzle so fragment reads stay
// conflict-free. Block: 128 tokens x 2816 codes (one third), 176 stages.
// ---------------------------------------------------------------------------
__launch_bounds__(256, 2)
__global__ void k_argmin(const _Float16* __restrict__ eh,
                         const _Float16* __restrict__ el,
                         const _Float16* __restrict__ cbh,
                         const _Float16* __restrict__ cbl,
                         const float* __restrict__ cbsq,
                         unsigned long long* __restrict__ packed) {
    __shared__ __align__(16) _Float16 sm[2][4][TM * BK];   // 64 KiB (dbuf)
    __shared__ float cand_v[2][TM];
    __shared__ int   cand_i[2][TM];

    const int t    = threadIdx.x;
    const int lane = t & 63;
    const int wave = t >> 6;
    const int wx   = wave & 1;        // code half (64 codes)
    const int wy   = wave >> 1;       // token half (64 tokens)
    const int lr   = lane & 15;
    const int koq  = lane >> 4;       // k-chunk (quad) for fragments

    const int n0 = blockIdx.x * TM;
    const int jq = blockIdx.y * JQ;

    // DMA assignment: wave w stages array w. Per-lane source chunk applies
    // the inverse swizzle: q = (lane&3) ^ ((lane>>3)&3)  (i*16 doesn't affect
    // (row>>1)&3 since 8 | i*8). Row within issue i: r = i*16 + (lane>>2).
    const _Float16* dsrc = (wave == 0) ? eh : (wave == 1) ? el
                         : (wave == 2) ? cbh : cbl;
    const int qsw   = (lane & 3) ^ ((lane >> 3) & 3);
    const int lrow  = lane >> 2;

    float minv[16];
    int   mini[16];
    #pragma unroll
    for (int e = 0; e < 16; ++e) { minv[e] = 3.402823466e38f; mini[e] = 0; }

    floatx4 acc[4][4];
    #pragma unroll
    for (int mf = 0; mf < 4; ++mf)
        #pragma unroll
        for (int nf = 0; nf < 4; ++nf)
            acc[mf][nf] = (floatx4){0.f, 0.f, 0.f, 0.f};

    // DMA of stage sg into buffer buf (8 x 1KB per wave).
    auto dma = [&](int buf, int sg) {
        const int c0 = (sg & 7) * BK;
        const int jb = jq + (sg >> 3) * TN;
        const int rb = (wave < 2) ? n0 : jb;
        const _Float16* gbase = dsrc + (size_t)(rb + lrow) * CH + c0 + qsw * 8;
        #pragma unroll
        for (int i = 0; i < 8; ++i) {
            const _Float16* g = gbase + (size_t)(i * 16) * CH;
            __builtin_amdgcn_global_load_lds(
                (guint_t*)g, (luint_t*)&sm[buf][wave][i * 512], 16, 0, 0);
        }
    };

    // prologue: stage 0 -> buf 0
    dma(0, 0);

    #pragma unroll 1
    for (int s = 0; s < NSTG; ++s) {
        const int cur = s & 1;

        // ---- prefetch stage s+1 into the other buffer, then wait only for
        //      stage s's 8 loads (the 8 just issued stay in flight) ----
        if (s + 1 < NSTG) {
            dma(cur ^ 1, s + 1);
            asm volatile("s_waitcnt vmcnt(8)" ::: "memory");
        } else {
            asm volatile("s_waitcnt vmcnt(0)" ::: "memory");
        }
        __builtin_amdgcn_s_barrier();         // everyone's stage-s data in LDS
        __builtin_amdgcn_sched_barrier(0);

        // ---- fragments + MFMA from sm[cur] ----
        half8_t fah[4], fal[4];
        #pragma unroll
        for (int mf = 0; mf < 4; ++mf) {
            int off = swz(wy * 64 + mf * 16 + lr, koq);
            fah[mf] = *(const half8_t*)&sm[cur][0][off];
            fal[mf] = *(const half8_t*)&sm[cur][1][off];
        }
        __builtin_amdgcn_s_setprio(1);
        #pragma unroll
        for (int nf = 0; nf < 4; ++nf) {
            int offb = swz(wx * 64 + nf * 16 + lr, koq);
            half8_t fbh = *(const half8_t*)&sm[cur][2][offb];
            half8_t fbl = *(const half8_t*)&sm[cur][3][offb];
            #pragma unroll
            for (int mf = 0; mf < 4; ++mf) {
                acc[mf][nf] = __builtin_amdgcn_mfma_f32_16x16x32_f16(
                    fah[mf], fbh, acc[mf][nf], 0, 0, 0);
                acc[mf][nf] = __builtin_amdgcn_mfma_f32_16x16x32_f16(
                    fah[mf], fbl, acc[mf][nf], 0, 0, 0);
                acc[mf][nf] = __builtin_amdgcn_mfma_f32_16x16x32_f16(
                    fal[mf], fbh, acc[mf][nf], 0, 0, 0);
            }
        }
        __builtin_amdgcn_s_setprio(0);

        if ((s & 7) == 7) {           // end of a 128-code jt tile: fold
            int jbase = jq + (s >> 3) * TN;
            #pragma unroll
            for (int nf = 0; nf < 4; ++nf) {
                int j = jbase + wx * 64 + nf * 16 + lr;
                float sq = cbsq[j];
                #pragma unroll
                for (int mf = 0; mf < 4; ++mf) {
                    floatx4 a = acc[mf][nf];
                    #pragma unroll
                    for (int r = 0; r < 4; ++r) {
                        float sc = sq - 2.0f * a[r];
                        int e = mf * 4 + r;
                        if (sc < minv[e]) { minv[e] = sc; mini[e] = j; }
                    }
                    acc[mf][nf] = (floatx4){0.f, 0.f, 0.f, 0.f};
                }
            }
        }

        // ---- release: all LDS reads of sm[cur] done before any wave's
        //      next-iteration DMA overwrites it ----
        asm volatile("s_waitcnt lgkmcnt(0)" ::: "memory");
        __builtin_amdgcn_sched_barrier(0);
        __builtin_amdgcn_s_barrier();
    }

    // ---- epilogue: cross-lane then cross-wave argmin reduce ----
    #pragma unroll
    for (int e = 0; e < 16; ++e) {
        float v = minv[e];
        int   x = mini[e];
        #pragma unroll
        for (int m = 1; m <= 8; m <<= 1) {
            float ov = __shfl_xor(v, m, 64);
            int   ox = __shfl_xor(x, m, 64);
            if (ov < v || (ov == v && ox < x)) { v = ov; x = ox; }
        }
        if (lr == 0) {
            int row = wy * 64 + (e >> 2) * 16 + (lane >> 4) * 4 + (e & 3);
            cand_v[wx][row] = v;
            cand_i[wx][row] = x;
        }
    }
    __syncthreads();

    if (t < TM) {
        float v0 = cand_v[0][t]; int i0 = cand_i[0][t];
        float v1 = cand_v[1][t]; int i1 = cand_i[1][t];
        if (v1 < v0 || (v1 == v0 && i1 < i0)) { v0 = v1; i0 = i1; }
        unsigned sb = __float_as_uint(v0);
        sb = (sb & 0x80000000u) ? ~sb : (sb | 0x80000000u);
        unsigned long long key = ((unsigned long long)sb << 32) | (unsigned)i0;
        atomicMin(&packed[n0 + t], key);
    }
}

// ---------------------------------------------------------------------------
// Kernel 3: gather + straight-through + loss partials + histogram
// ---------------------------------------------------------------------------
__global__ void k_gather(const float* __restrict__ emb,
                         const float* __restrict__ ces,
                         const float* __restrict__ usage,
                         const unsigned long long* __restrict__ packed,
                         float* __restrict__ out_eq,
                         float* __restrict__ codes_f,
                         int* __restrict__ hist,
                         float* __restrict__ partials) {
    int t = threadIdx.x;
    int wave = t >> 6, lane = t & 63;
    int n = blockIdx.x * 4 + wave;
    int k = (int)(packed[n] & 0xFFFFFFFFull);
    float uc = fmaxf(usage[k], 1e-5f);
    int c = lane * 4;

    float4 e = *(const float4*)&emb[(size_t)n * CH + c];
    float4 v = *(const float4*)&ces[(size_t)k * CH + c];
    float ea[4] = {e.x, e.y, e.z, e.w};
    float va[4] = {v.x, v.y, v.z, v.w};
    float eqa[4];
    float p = 0.0f;
    #pragma unroll
    for (int q = 0; q < 4; ++q) {
        float cb = va[q] / uc;
        float eq = ea[q] + (cb - ea[q]);
        eqa[q] = eq;
        float d = eq - ea[q];
        p += d * d;
    }
    *(float4*)&out_eq[(size_t)n * CH + c] =
        (float4){eqa[0], eqa[1], eqa[2], eqa[3]};

    #pragma unroll
    for (int off = 32; off; off >>= 1) p += __shfl_down(p, off);
    __shared__ float ps[4];
    if (lane == 0) {
        ps[wave] = p;
        codes_f[n] = (float)k;
        atomicAdd(&hist[k], 1);
    }
    __syncthreads();
    if (t == 0) partials[blockIdx.x] = ps[0] + ps[1] + ps[2] + ps[3];
}

// ---------------------------------------------------------------------------
// Kernel 4: exclusive prefix sum over hist -> offs, cursor (1 block)
// ---------------------------------------------------------------------------
__global__ void k_scan(const int* __restrict__ hist,
                       int* __restrict__ offs,
                       int* __restrict__ cursor) {
    __shared__ int bs[256];
    int t = threadIdx.x;
    int base = t * 32;
    int loc[32];
    int s = 0;
    #pragma unroll
    for (int i = 0; i < 32; ++i) { loc[i] = s; s += hist[base + i]; }
    int mysum = s;
    bs[t] = s;
    __syncthreads();
    for (int off = 1; off < 256; off <<= 1) {
        int v = (t >= off) ? bs[t - off] : 0;
        __syncthreads();
        bs[t] += v;
        __syncthreads();
    }
    int excl = bs[t] - mysum;
    #pragma unroll
    for (int i = 0; i < 32; ++i) {
        int o = excl + loc[i];
        offs[base + i]   = o;
        cursor[base + i] = o;
    }
}

// ---------------------------------------------------------------------------
// Kernel 5: scatter token ids into code-sorted buckets
// ---------------------------------------------------------------------------
__global__ void k_scatter(const unsigned long long* __restrict__ packed,
                          int* __restrict__ cursor,
                          int* __restrict__ bucket) {
    int n = blockIdx.x * 256 + threadIdx.x;
    int k = (int)(packed[n] & 0xFFFFFFFFull);
    int pos = atomicAdd(&cursor[k], 1);
    bucket[pos] = n;
}

// ---------------------------------------------------------------------------
// Kernel 6: per-code EMA (one BLOCK per code: coalesced 1KB row loads,
// thread t owns channel t, no atomics, no wave-serial latency chain)
// ---------------------------------------------------------------------------
__global__ void k_ema(const float* __restrict__ emb,
                      const float* __restrict__ ces,
                      const float* __restrict__ usage,
                      const int* __restrict__ hist,
                      const int* __restrict__ offs,
                      const int* __restrict__ bucket,
                      float* __restrict__ out_ces,
                      float* __restrict__ out_usage) {
    const float s = 0.01f;
    const float oms = 1.0f - s;
    int k = blockIdx.x, t = threadIdx.x;
    int start = offs[k], cnt = hist[k];
    float sum = 0.0f;
    #pragma unroll 2
    for (int i = 0; i < cnt; ++i) {
        int n = bucket[start + i];            // block-uniform (scalar) load
        sum += emb[(size_t)n * CH + t];       // coalesced row
    }
    out_ces[(size_t)k * CH + t] = oms * ces[(size_t)k * CH + t] + s * sum;
    if (t == 0) out_usage[k] = oms * usage[k] + s * (float)cnt;
}

// ---------------------------------------------------------------------------
// Kernel 7: reduce loss partials, mean over 2^23 elements
// ---------------------------------------------------------------------------
__global__ void k_final(const float* __restrict__ partials,
                        float* __restrict__ out_loss) {
    int t = threadIdx.x;
    float p = 0.0f;
    for (int i = t; i < NT / 4; i += 256) p += partials[i];
    #pragma unroll
    for (int off = 32; off; off >>= 1) p += __shfl_down(p, off);
    __shared__ float ps[4];
    if ((t & 63) == 0) ps[t >> 6] = p;
    __syncthreads();
    if (t == 0)
        out_loss[0] = (ps[0] + ps[1] + ps[2] + ps[3]) * (1.0f / 8388608.0f);
}

extern "C" void kernel_launch(void* const* d_in, const int* in_sizes, int n_in,
                              void* d_out, int out_size, void* d_ws, size_t ws_size,
                              hipStream_t stream) {
    const float* emb   = (const float*)d_in[0];  // [32768, 256]
    const float* usage = (const float*)d_in[1];  // [8192]
    const float* ces   = (const float*)d_in[2];  // [8192, 256]

    float* out      = (float*)d_out;
    float* o_codes  = out;                       // 32768
    float* o_eq     = out + NT;                  // 8388608
    float* o_loss   = o_eq + (size_t)NT * CH;    // 1
    float* o_usage  = o_loss + 1;                // 8192
    float* o_ces    = o_usage + KC;              // 2097152

    unsigned long long* packed = (unsigned long long*)d_ws;   // NT u64
    float* cbsq     = (float*)(packed + NT);                  // KCP
    float* partials = cbsq + KCP;                             // NT/4
    int* hist   = (int*)(partials + NT / 4);                  // KC
    int* offs   = hist + KC;                                  // KC
    int* cursor = offs + KC;                                  // KC
    int* bucket = cursor + KC;                                // NT
    _Float16* eh  = (_Float16*)(bucket + NT);                 // NT*CH
    _Float16* el  = eh + (size_t)NT * CH;
    _Float16* cbh = el + (size_t)NT * CH;                     // KCP*CH
    _Float16* cbl = cbh + (size_t)KCP * CH;

    k_prep<<<KCP + NT * CH / 1024, 256, 0, stream>>>(
        usage, ces, emb, cbh, cbl, cbsq, eh, el, hist, packed);
    dim3 agrid(NT / TM, YS);
    k_argmin<<<agrid, 256, 0, stream>>>(eh, el, cbh, cbl, cbsq, packed);
    k_gather<<<NT / 4, 256, 0, stream>>>(emb, ces, usage, packed, o_eq,
                                         o_codes, hist, partials);
    k_scan<<<1, 256, 0, stream>>>(hist, offs, cursor);
    k_scatter<<<NT / 256, 256, 0, stream>>>(packed, cursor, bucket);
    k_ema<<<KC, 256, 0, stream>>>(emb, ces, usage, hist, offs, bucket,
                                  o_ces, o_usage);
    k_final<<<1, 256, 0, stream>>>(partials, o_loss);
}

// Round 2
// 675.182 us; speedup vs baseline: 1.0470x; 1.0470x over previous
//
#include <hip/hip_runtime.h>

#define CH 256
#define KC 8192
#define NT 32768

#define TM 128         // tokens per block
#define TN 128         // codes per jt tile
#define BK 32          // channels staged per stage
#define YS 2           // code halves (512 blocks = exactly 2/CU, no tail)
#define JQ (KC / YS)   // 4096 codes per block, zero padding
#define NSTG ((JQ / TN) * (CH / BK))   // 32 jt * 8 c0 = 256 stages

typedef _Float16 half4_t __attribute__((ext_vector_type(4)));
typedef _Float16 half8_t __attribute__((ext_vector_type(8)));
typedef float floatx4 __attribute__((ext_vector_type(4)));

typedef __attribute__((address_space(1))) const unsigned int guint_t;
typedef __attribute__((address_space(3))) unsigned int luint_t;

// XOR-swizzled LDS offset (halves) for row-major [row][BK] tiles, 16B chunks.
__device__ __forceinline__ int swz(int row, int chunk) {
    return row * BK + ((chunk ^ ((row >> 1) & 3)) << 3);
}

// ---------------------------------------------------------------------------
// Kernel 1 (fused prep):
//  blocks [0, KC):   codebook row -> fp16 hi/lo + cbsq, zero hist, init keys
//  blocks [KC, ...): split embeddings fp32 -> fp16 hi/lo (1 float4/thread)
// ---------------------------------------------------------------------------
__global__ void k_prep(const float* __restrict__ usage,
                       const float* __restrict__ ces,
                       const float* __restrict__ emb,
                       _Float16* __restrict__ cbh,
                       _Float16* __restrict__ cbl,
                       float* __restrict__ cbsq,
                       _Float16* __restrict__ eh,
                       _Float16* __restrict__ el,
                       int* __restrict__ hist,
                       unsigned long long* __restrict__ packed) {
    int b = blockIdx.x, t = threadIdx.x;
    if (b < KC) {
        float uc = fmaxf(usage[b], 1e-5f);
        float v  = ces[b * CH + t];
        float cb = v / uc;
        _Float16 h = (_Float16)cb;
        cbh[b * CH + t] = h;
        cbl[b * CH + t] = (_Float16)(cb - (float)h);

        float p = cb * cb;
        #pragma unroll
        for (int off = 32; off; off >>= 1) p += __shfl_down(p, off);
        __shared__ float ps[4];
        int lane = t & 63, w = t >> 6;
        if (lane == 0) ps[w] = p;
        __syncthreads();
        if (t == 0) cbsq[b] = ps[0] + ps[1] + ps[2] + ps[3];
        if (t == 1) hist[b] = 0;
        int gid = b * CH + t;
        if (gid < NT) packed[gid] = 0xFFFFFFFFFFFFFFFFull;
    } else {
        int i = (b - KC) * 256 + t;      // float4 index
        float4 v = ((const float4*)emb)[i];
        float va[4] = {v.x, v.y, v.z, v.w};
        half4_t h, l;
        #pragma unroll
        for (int q = 0; q < 4; ++q) {
            _Float16 hh = (_Float16)va[q];
            h[q] = hh;
            l[q] = (_Float16)(va[q] - (float)hh);
        }
        ((half4_t*)eh)[i] = h;
        ((half4_t*)el)[i] = l;
    }
}

// ---------------------------------------------------------------------------
// Kernel 2: fp16-split MFMA argmin.
// 2x32KB double-buffered LDS via global_load_lds (16B DMA). One-barrier
// 2-phase schedule (guide T3 minimum form): after the rendezvous, issue
// stage s+1's DMA into buf^1 (consumed before the PREVIOUS rendezvous),
// compute stage s, then vmcnt(0)+s_barrier. DMA latency hides under the
// full compute phase. XCD swizzle: id%8 -> XCD; XCDs 0-3 take y=0,
// 4-7 take y=1, so each XCD's 4MiB L2 re-serves one 4.19MB B-half and
// only the A-panel stream goes to L3. cbsq is prefetched at jt-start
// (7 stages before use, issued before the DMA batch) so the fold never
// drains the prefetch pipeline.
// ---------------------------------------------------------------------------
__launch_bounds__(256, 2)
__global__ void k_argmin(const _Float16* __restrict__ eh,
                         const _Float16* __restrict__ el,
                         const _Float16* __restrict__ cbh,
                         const _Float16* __restrict__ cbl,
                         const float* __restrict__ cbsq,
                         unsigned long long* __restrict__ packed) {
    __shared__ __align__(16) _Float16 sm[2][4][TM * BK];   // 64 KiB (dbuf)
    __shared__ float cand_v[2][TM];
    __shared__ int   cand_i[2][TM];

    const int t    = threadIdx.x;
    const int lane = t & 63;
    const int wave = t >> 6;
    const int wx   = wave & 1;        // code half (64 codes)
    const int wy   = wave >> 1;       // token half (64 tokens)
    const int lr   = lane & 15;
    const int koq  = lane >> 4;       // k-chunk (quad) for fragments

    // XCD-locality swizzle (id%8 round-robins XCDs): y = xcd>>2, so each
    // XCD sees a single B-half; x packs 4 consecutive blocks per XCD group.
    const int id  = blockIdx.x;
    const int xcd = id & 7;
    const int n0  = ((id >> 3) * 4 + (xcd & 3)) * TM;
    const int jq  = (xcd >> 2) * JQ;

    // DMA assignment: wave w stages array w. Per-lane source chunk applies
    // the inverse swizzle: q = (lane&3) ^ ((lane>>3)&3)  (i*16 doesn't affect
    // (row>>1)&3 since 8 | i*8). Row within issue i: r = i*16 + (lane>>2).
    const _Float16* dsrc = (wave == 0) ? eh : (wave == 1) ? el
                         : (wave == 2) ? cbh : cbl;
    const int qsw   = (lane & 3) ^ ((lane >> 3) & 3);
    const int lrow  = lane >> 2;

    float minv[16];
    int   mini[16];
    #pragma unroll
    for (int e = 0; e < 16; ++e) { minv[e] = 3.402823466e38f; mini[e] = 0; }

    floatx4 acc[4][4];
    #pragma unroll
    for (int mf = 0; mf < 4; ++mf)
        #pragma unroll
        for (int nf = 0; nf < 4; ++nf)
            acc[mf][nf] = (floatx4){0.f, 0.f, 0.f, 0.f};

    // DMA of stage sg into buffer buf (8 x 1KB per wave).
    auto dma = [&](int buf, int sg) {
        const int c0 = (sg & 7) * BK;
        const int jb = jq + (sg >> 3) * TN;
        const int rb = (wave < 2) ? n0 : jb;
        const _Float16* gbase = dsrc + (size_t)(rb + lrow) * CH + c0 + qsw * 8;
        #pragma unroll
        for (int i = 0; i < 8; ++i) {
            const _Float16* g = gbase + (size_t)(i * 16) * CH;
            __builtin_amdgcn_global_load_lds(
                (guint_t*)g, (luint_t*)&sm[buf][wave][i * 512], 16, 0, 0);
        }
    };

    // prologue: stage 0 -> buf 0, drain, rendezvous
    dma(0, 0);
    asm volatile("s_waitcnt vmcnt(0)" ::: "memory");
    __builtin_amdgcn_s_barrier();
    __builtin_amdgcn_sched_barrier(0);

    float csq[4] = {0.f, 0.f, 0.f, 0.f};

    #pragma unroll 1
    for (int s = 0; s < NSTG; ++s) {
        const int cur = s & 1;

        // cbsq prefetch for this jt (used 7 stages later). Issued BEFORE the
        // DMA batch so the compiler's use-wait resolves at vmcnt(8): the
        // in-flight prefetch survives the fold.
        if ((s & 7) == 0) {
            int jbase = jq + (s >> 3) * TN;
            #pragma unroll
            for (int nf = 0; nf < 4; ++nf)
                csq[nf] = cbsq[jbase + wx * 64 + nf * 16 + lr];
        }

        // issue next stage into the other buffer (its last readers finished
        // before the PREVIOUS rendezvous)
        if (s + 1 < NSTG) dma(cur ^ 1, s + 1);

        // ---- fragments + MFMA from sm[cur] ----
        half8_t fah[4], fal[4];
        #pragma unroll
        for (int mf = 0; mf < 4; ++mf) {
            int off = swz(wy * 64 + mf * 16 + lr, koq);
            fah[mf] = *(const half8_t*)&sm[cur][0][off];
            fal[mf] = *(const half8_t*)&sm[cur][1][off];
        }
        __builtin_amdgcn_s_setprio(1);
        #pragma unroll
        for (int nf = 0; nf < 4; ++nf) {
            int offb = swz(wx * 64 + nf * 16 + lr, koq);
            half8_t fbh = *(const half8_t*)&sm[cur][2][offb];
            half8_t fbl = *(const half8_t*)&sm[cur][3][offb];
            #pragma unroll
            for (int mf = 0; mf < 4; ++mf) {
                acc[mf][nf] = __builtin_amdgcn_mfma_f32_16x16x32_f16(
                    fah[mf], fbh, acc[mf][nf], 0, 0, 0);
                acc[mf][nf] = __builtin_amdgcn_mfma_f32_16x16x32_f16(
                    fah[mf], fbl, acc[mf][nf], 0, 0, 0);
                acc[mf][nf] = __builtin_amdgcn_mfma_f32_16x16x32_f16(
                    fal[mf], fbh, acc[mf][nf], 0, 0, 0);
            }
        }
        __builtin_amdgcn_s_setprio(0);

        if ((s & 7) == 7) {           // end of a 128-code jt tile: fold
            int jbase = jq + (s >> 3) * TN;
            #pragma unroll
            for (int nf = 0; nf < 4; ++nf) {
                int j = jbase + wx * 64 + nf * 16 + lr;
                float sq = csq[nf];
                #pragma unroll
                for (int mf = 0; mf < 4; ++mf) {
                    floatx4 a = acc[mf][nf];
                    #pragma unroll
                    for (int r = 0; r < 4; ++r) {
                        float sc = sq - 2.0f * a[r];
                        int e = mf * 4 + r;
                        if (sc < minv[e]) { minv[e] = sc; mini[e] = j; }
                    }
                    acc[mf][nf] = (floatx4){0.f, 0.f, 0.f, 0.f};
                }
            }
        }

        // single rendezvous per stage: stage s+1 complete in LDS, and all
        // waves' reads of sm[cur] were consumed (MFMA data deps) before here.
        asm volatile("s_waitcnt vmcnt(0)" ::: "memory");
        __builtin_amdgcn_sched_barrier(0);
        __builtin_amdgcn_s_barrier();
        __builtin_amdgcn_sched_barrier(0);
    }

    // ---- epilogue: cross-lane then cross-wave argmin reduce ----
    #pragma unroll
    for (int e = 0; e < 16; ++e) {
        float v = minv[e];
        int   x = mini[e];
        #pragma unroll
        for (int m = 1; m <= 8; m <<= 1) {
            float ov = __shfl_xor(v, m, 64);
            int   ox = __shfl_xor(x, m, 64);
            if (ov < v || (ov == v && ox < x)) { v = ov; x = ox; }
        }
        if (lr == 0) {
            int row = wy * 64 + (e >> 2) * 16 + (lane >> 4) * 4 + (e & 3);
            cand_v[wx][row] = v;
            cand_i[wx][row] = x;
        }
    }
    __syncthreads();

    if (t < TM) {
        float v0 = cand_v[0][t]; int i0 = cand_i[0][t];
        float v1 = cand_v[1][t]; int i1 = cand_i[1][t];
        if (v1 < v0 || (v1 == v0 && i1 < i0)) { v0 = v1; i0 = i1; }
        unsigned sb = __float_as_uint(v0);
        sb = (sb & 0x80000000u) ? ~sb : (sb | 0x80000000u);
        unsigned long long key = ((unsigned long long)sb << 32) | (unsigned)i0;
        atomicMin(&packed[n0 + t], key);
    }
}

// ---------------------------------------------------------------------------
// Kernel 3: gather + straight-through + loss partials + histogram
// ---------------------------------------------------------------------------
__global__ void k_gather(const float* __restrict__ emb,
                         const float* __restrict__ ces,
                         const float* __restrict__ usage,
                         const unsigned long long* __restrict__ packed,
                         float* __restrict__ out_eq,
                         float* __restrict__ codes_f,
                         int* __restrict__ hist,
                         float* __restrict__ partials) {
    int t = threadIdx.x;
    int wave = t >> 6, lane = t & 63;
    int n = blockIdx.x * 4 + wave;
    int k = (int)(packed[n] & 0xFFFFFFFFull);
    float uc = fmaxf(usage[k], 1e-5f);
    int c = lane * 4;

    float4 e = *(const float4*)&emb[(size_t)n * CH + c];
    float4 v = *(const float4*)&ces[(size_t)k * CH + c];
    float ea[4] = {e.x, e.y, e.z, e.w};
    float va[4] = {v.x, v.y, v.z, v.w};
    float eqa[4];
    float p = 0.0f;
    #pragma unroll
    for (int q = 0; q < 4; ++q) {
        float cb = va[q] / uc;
        float eq = ea[q] + (cb - ea[q]);
        eqa[q] = eq;
        float d = eq - ea[q];
        p += d * d;
    }
    *(float4*)&out_eq[(size_t)n * CH + c] =
        (float4){eqa[0], eqa[1], eqa[2], eqa[3]};

    #pragma unroll
    for (int off = 32; off; off >>= 1) p += __shfl_down(p, off);
    __shared__ float ps[4];
    if (lane == 0) {
        ps[wave] = p;
        codes_f[n] = (float)k;
        atomicAdd(&hist[k], 1);
    }
    __syncthreads();
    if (t == 0) partials[blockIdx.x] = ps[0] + ps[1] + ps[2] + ps[3];
}

// ---------------------------------------------------------------------------
// Kernel 4: exclusive prefix sum over hist -> offs, cursor (1 block)
// ---------------------------------------------------------------------------
__global__ void k_scan(const int* __restrict__ hist,
                       int* __restrict__ offs,
                       int* __restrict__ cursor) {
    __shared__ int bs[256];
    int t = threadIdx.x;
    int base = t * 32;
    int loc[32];
    int s = 0;
    #pragma unroll
    for (int i = 0; i < 32; ++i) { loc[i] = s; s += hist[base + i]; }
    int mysum = s;
    bs[t] = s;
    __syncthreads();
    for (int off = 1; off < 256; off <<= 1) {
        int v = (t >= off) ? bs[t - off] : 0;
        __syncthreads();
        bs[t] += v;
        __syncthreads();
    }
    int excl = bs[t] - mysum;
    #pragma unroll
    for (int i = 0; i < 32; ++i) {
        int o = excl + loc[i];
        offs[base + i]   = o;
        cursor[base + i] = o;
    }
}

// ---------------------------------------------------------------------------
// Kernel 5: scatter token ids into code-sorted buckets
// ---------------------------------------------------------------------------
__global__ void k_scatter(const unsigned long long* __restrict__ packed,
                          int* __restrict__ cursor,
                          int* __restrict__ bucket) {
    int n = blockIdx.x * 256 + threadIdx.x;
    int k = (int)(packed[n] & 0xFFFFFFFFull);
    int pos = atomicAdd(&cursor[k], 1);
    bucket[pos] = n;
}

// ---------------------------------------------------------------------------
// Kernel 6: per-code EMA (one BLOCK per code: coalesced 1KB row loads,
// thread t owns channel t, no atomics, no wave-serial latency chain)
// ---------------------------------------------------------------------------
__global__ void k_ema(const float* __restrict__ emb,
                      const float* __restrict__ ces,
                      const float* __restrict__ usage,
                      const int* __restrict__ hist,
                      const int* __restrict__ offs,
                      const int* __restrict__ bucket,
                      float* __restrict__ out_ces,
                      float* __restrict__ out_usage) {
    const float s = 0.01f;
    const float oms = 1.0f - s;
    int k = blockIdx.x, t = threadIdx.x;
    int start = offs[k], cnt = hist[k];
    float sum = 0.0f;
    #pragma unroll 2
    for (int i = 0; i < cnt; ++i) {
        int n = bucket[start + i];            // block-uniform (scalar) load
        sum += emb[(size_t)n * CH + t];       // coalesced row
    }
    out_ces[(size_t)k * CH + t] = oms * ces[(size_t)k * CH + t] + s * sum;
    if (t == 0) out_usage[k] = oms * usage[k] + s * (float)cnt;
}

// ---------------------------------------------------------------------------
// Kernel 7: reduce loss partials, mean over 2^23 elements
// ---------------------------------------------------------------------------
__global__ void k_final(const float* __restrict__ partials,
                        float* __restrict__ out_loss) {
    int t = threadIdx.x;
    float p = 0.0f;
    for (int i = t; i < NT / 4; i += 256) p += partials[i];
    #pragma unroll
    for (int off = 32; off; off >>= 1) p += __shfl_down(p, off);
    __shared__ float ps[4];
    if ((t & 63) == 0) ps[t >> 6] = p;
    __syncthreads();
    if (t == 0)
        out_loss[0] = (ps[0] + ps[1] + ps[2] + ps[3]) * (1.0f / 8388608.0f);
}

extern "C" void kernel_launch(void* const* d_in, const int* in_sizes, int n_in,
                              void* d_out, int out_size, void* d_ws, size_t ws_size,
                              hipStream_t stream) {
    const float* emb   = (const float*)d_in[0];  // [32768, 256]
    const float* usage = (const float*)d_in[1];  // [8192]
    const float* ces   = (const float*)d_in[2];  // [8192, 256]

    float* out      = (float*)d_out;
    float* o_codes  = out;                       // 32768
    float* o_eq     = out + NT;                  // 8388608
    float* o_loss   = o_eq + (size_t)NT * CH;    // 1
    float* o_usage  = o_loss + 1;                // 8192
    float* o_ces    = o_usage + KC;              // 2097152

    unsigned long long* packed = (unsigned long long*)d_ws;   // NT u64
    float* cbsq     = (float*)(packed + NT);                  // KC
    float* partials = cbsq + KC;                              // NT/4
    int* hist   = (int*)(partials + NT / 4);                  // KC
    int* offs   = hist + KC;                                  // KC
    int* cursor = offs + KC;                                  // KC
    int* bucket = cursor + KC;                                // NT
    _Float16* eh  = (_Float16*)(bucket + NT);                 // NT*CH
    _Float16* el  = eh + (size_t)NT * CH;
    _Float16* cbh = el + (size_t)NT * CH;                     // KC*CH
    _Float16* cbl = cbh + (size_t)KC * CH;

    k_prep<<<KC + NT * CH / 1024, 256, 0, stream>>>(
        usage, ces, emb, cbh, cbl, cbsq, eh, el, hist, packed);
    k_argmin<<<(NT / TM) * YS, 256, 0, stream>>>(eh, el, cbh, cbl, cbsq,
                                                 packed);
    k_gather<<<NT / 4, 256, 0, stream>>>(emb, ces, usage, packed, o_eq,
                                         o_codes, hist, partials);
    k_scan<<<1, 256, 0, stream>>>(hist, offs, cursor);
    k_scatter<<<NT / 256, 256, 0, stream>>>(packed, cursor, bucket);
    k_ema<<<KC, 256, 0, stream>>>(emb, ces, usage, hist, offs, bucket,
                                  o_ces, o_usage);
    k_final<<<1, 256, 0, stream>>>(partials, o_loss);
}

// Round 3
// 595.168 us; speedup vs baseline: 1.1878x; 1.1344x over previous
//
#include <hip/hip_runtime.h>

#define CH 256
#define KC 8192
#define NT 32768

#define TM 128         // tokens per block (A persistent in LDS)
#define TN 128         // codes per jt tile
#define BK 32          // channels staged per B stage
#define NSTG ((KC / TN) * (CH / BK))   // 64 jt * 8 c0 = 512 stages

typedef _Float16 half4_t __attribute__((ext_vector_type(4)));
typedef _Float16 half8_t __attribute__((ext_vector_type(8)));
typedef float floatx4 __attribute__((ext_vector_type(4)));

typedef __attribute__((address_space(1))) const unsigned int guint_t;
typedef __attribute__((address_space(3))) unsigned int luint_t;

// XOR-swizzled LDS offset (halves) for row-major [row][BK] tiles, 16B chunks.
__device__ __forceinline__ int swz(int row, int chunk) {
    return row * BK + ((chunk ^ ((row >> 1) & 3)) << 3);
}

// ---------------------------------------------------------------------------
// Kernel 1 (fused prep):
//  blocks [0, KC):   codebook row -> fp16 hi/lo + cbsq, zero hist
//  blocks [KC, ...): split embeddings fp32 -> fp16 hi/lo (1 float4/thread)
// (packed init removed: k_argmin now writes each token exactly once.)
// ---------------------------------------------------------------------------
__global__ void k_prep(const float* __restrict__ usage,
                       const float* __restrict__ ces,
                       const float* __restrict__ emb,
                       _Float16* __restrict__ cbh,
                       _Float16* __restrict__ cbl,
                       float* __restrict__ cbsq,
                       _Float16* __restrict__ eh,
                       _Float16* __restrict__ el,
                       int* __restrict__ hist) {
    int b = blockIdx.x, t = threadIdx.x;
    if (b < KC) {
        float uc = fmaxf(usage[b], 1e-5f);
        float v  = ces[b * CH + t];
        float cb = v / uc;
        _Float16 h = (_Float16)cb;
        cbh[b * CH + t] = h;
        cbl[b * CH + t] = (_Float16)(cb - (float)h);

        float p = cb * cb;
        #pragma unroll
        for (int off = 32; off; off >>= 1) p += __shfl_down(p, off);
        __shared__ float ps[4];
        int lane = t & 63, w = t >> 6;
        if (lane == 0) ps[w] = p;
        __syncthreads();
        if (t == 0) cbsq[b] = ps[0] + ps[1] + ps[2] + ps[3];
        if (t == 1) hist[b] = 0;
    } else {
        int i = (b - KC) * 256 + t;      // float4 index
        float4 v = ((const float4*)emb)[i];
        float va[4] = {v.x, v.y, v.z, v.w};
        half4_t h, l;
        #pragma unroll
        for (int q = 0; q < 4; ++q) {
            _Float16 hh = (_Float16)va[q];
            h[q] = hh;
            l[q] = (_Float16)(va[q] - (float)hh);
        }
        ((half4_t*)eh)[i] = h;
        ((half4_t*)el)[i] = l;
    }
}

// ---------------------------------------------------------------------------
// Kernel 2: fp16-split MFMA argmin, A-persistent restructure.
// One block per 128-token panel (grid=256 = 1 block/CU, no tail). The full
// A tile (128 tokens x 256 ch, hi+lo fp16 = 128 KiB) is DMA'd into LDS ONCE;
// only B (codebook) streams: 512 stages x 16 KiB, double-buffered with the
// one-barrier schedule (issue s+1's DMA, compute s, vmcnt(0)+s_barrier).
// Global staging traffic drops 6.5 GB -> 2.2 GB; all blocks sweep jt in the
// same order so each 16 KiB B stage is L2-hot across the XCD's 32 blocks.
// 8 waves: wave = (token half wy) x (code quarter wx); per-stage 24 MFMA/wave.
// Each token's argmin completes in-block -> plain u64 store, no atomics.
// LDS: 128 KiB A + 32 KiB B dbuf = 160 KiB; epilogue cand aliases B region.
// ---------------------------------------------------------------------------
__launch_bounds__(512, 1)
__global__ void k_argmin(const _Float16* __restrict__ eh,
                         const _Float16* __restrict__ el,
                         const _Float16* __restrict__ cbh,
                         const _Float16* __restrict__ cbl,
                         const float* __restrict__ cbsq,
                         unsigned long long* __restrict__ packed) {
    __shared__ __align__(16) unsigned char smraw[163840];
    _Float16* smA = (_Float16*)smraw;             // [hi/lo][8 cc][128*32] halves
    _Float16* smB = (_Float16*)(smraw + 131072);  // [2 buf][hi/lo][128*32]

    const int t    = threadIdx.x;
    const int lane = t & 63;
    const int wave = t >> 6;          // 0..7
    const int wx   = wave & 3;        // code quarter (32 codes)
    const int wy   = wave >> 2;       // token half (64 tokens)
    const int lr   = lane & 15;
    const int koq  = lane >> 4;       // k-chunk (quad) for fragments

    const int n0 = blockIdx.x * TM;

    // DMA lane mapping with inverse swizzle pre-applied to the global source:
    // q = (lane&3) ^ ((lane>>3)&3), row-within-load = lane>>2.
    const int qsw  = (lane & 3) ^ ((lane >> 3) & 3);
    const int lrow = lane >> 2;

    // DMA roles: waves 0-3 stage the hi array, 4-7 the lo array.
    const int hl = wave >> 2;
    const _Float16* asrc = hl ? el : eh;
    const _Float16* bsrc = hl ? cbl : cbh;

    float minv[16];
    int   mini[16];
    #pragma unroll
    for (int e = 0; e < 16; ++e) { minv[e] = 3.402823466e38f; mini[e] = 0; }

    floatx4 acc[4][2];
    #pragma unroll
    for (int mf = 0; mf < 4; ++mf)
        #pragma unroll
        for (int nf = 0; nf < 2; ++nf)
            acc[mf][nf] = (floatx4){0.f, 0.f, 0.f, 0.f};

    // ---- prologue: A tile (once) + B stage 0, drain, rendezvous ----
    {
        const int ccb = (wave & 3) * 2;   // 2 channel-chunks per wave
        #pragma unroll
        for (int d = 0; d < 2; ++d) {
            const int cc = ccb + d;
            const _Float16* g0 = asrc + (size_t)(n0 + lrow) * CH + cc * BK
                               + qsw * 8;
            #pragma unroll
            for (int i = 0; i < 8; ++i) {
                __builtin_amdgcn_global_load_lds(
                    (guint_t*)(g0 + (size_t)(i * 16) * CH),
                    (luint_t*)&smA[hl * 32768 + cc * 4096 + i * 512], 16, 0, 0);
            }
        }
    }

    // B stage DMA: wave (hl, wx) loads rows [wx*32, wx*32+32) of cb{h,l}.
    auto dmaB = [&](int buf, int sg) {
        const int c0 = (sg & 7) * BK;
        const int jb = (sg >> 3) * TN + wx * 32;
        const _Float16* g0 = bsrc + (size_t)(jb + lrow) * CH + c0 + qsw * 8;
        #pragma unroll
        for (int i = 0; i < 2; ++i) {
            __builtin_amdgcn_global_load_lds(
                (guint_t*)(g0 + (size_t)(i * 16) * CH),
                (luint_t*)&smB[buf * 8192 + hl * 4096 + wx * 1024 + i * 512],
                16, 0, 0);
        }
    };

    dmaB(0, 0);
    asm volatile("s_waitcnt vmcnt(0)" ::: "memory");
    __builtin_amdgcn_s_barrier();
    __builtin_amdgcn_sched_barrier(0);

    float csq[2] = {0.f, 0.f};

    #pragma unroll 1
    for (int s = 0; s < NSTG; ++s) {
        const int cur = s & 1;
        const int cc  = s & 7;

        // cbsq prefetch for this jt tile (used 7 stages later at the fold).
        if ((s & 7) == 0) {
            int jbase = (s >> 3) * TN;
            #pragma unroll
            for (int nf = 0; nf < 2; ++nf)
                csq[nf] = cbsq[jbase + wx * 32 + nf * 16 + lr];
        }

        // issue next B stage into the other buffer (its readers finished
        // before the previous rendezvous)
        if (s + 1 < NSTG) dmaB(cur ^ 1, s + 1);

        // ---- fragments + MFMA ----
        half8_t fah[4], fal[4];
        #pragma unroll
        for (int mf = 0; mf < 4; ++mf) {
            int off = cc * 4096 + swz(wy * 64 + mf * 16 + lr, koq);
            fah[mf] = *(const half8_t*)&smA[off];
            fal[mf] = *(const half8_t*)&smA[32768 + off];
        }
        __builtin_amdgcn_s_setprio(1);
        #pragma unroll
        for (int nf = 0; nf < 2; ++nf) {
            int offb = cur * 8192 + swz(wx * 32 + nf * 16 + lr, koq);
            half8_t fbh = *(const half8_t*)&smB[offb];
            half8_t fbl = *(const half8_t*)&smB[4096 + offb];
            #pragma unroll
            for (int mf = 0; mf < 4; ++mf) {
                acc[mf][nf] = __builtin_amdgcn_mfma_f32_16x16x32_f16(
                    fah[mf], fbh, acc[mf][nf], 0, 0, 0);
                acc[mf][nf] = __builtin_amdgcn_mfma_f32_16x16x32_f16(
                    fah[mf], fbl, acc[mf][nf], 0, 0, 0);
                acc[mf][nf] = __builtin_amdgcn_mfma_f32_16x16x32_f16(
                    fal[mf], fbh, acc[mf][nf], 0, 0, 0);
            }
        }
        __builtin_amdgcn_s_setprio(0);

        if ((s & 7) == 7) {           // end of a 128-code jt tile: fold
            int jbase = (s >> 3) * TN;
            #pragma unroll
            for (int nf = 0; nf < 2; ++nf) {
                int j = jbase + wx * 32 + nf * 16 + lr;
                float sq = csq[nf];
                #pragma unroll
                for (int mf = 0; mf < 4; ++mf) {
                    floatx4 a = acc[mf][nf];
                    #pragma unroll
                    for (int r = 0; r < 4; ++r) {
                        float sc = sq - 2.0f * a[r];
                        int e = mf * 4 + r;
                        if (sc < minv[e]) { minv[e] = sc; mini[e] = j; }
                    }
                    acc[mf][nf] = (floatx4){0.f, 0.f, 0.f, 0.f};
                }
            }
        }

        // single rendezvous per stage
        asm volatile("s_waitcnt vmcnt(0)" ::: "memory");
        __builtin_amdgcn_sched_barrier(0);
        __builtin_amdgcn_s_barrier();
        __builtin_amdgcn_sched_barrier(0);
    }

    // ---- epilogue: cross-lane reduce, then cross-quarter via LDS ----
    // cand arrays alias the (now dead) B double-buffer region.
    float* cand_v = (float*)(smraw + 131072);          // [4][TM]
    int*   cand_i = (int*)(smraw + 131072 + 4 * TM * 4);

    #pragma unroll
    for (int e = 0; e < 16; ++e) {
        float v = minv[e];
        int   x = mini[e];
        #pragma unroll
        for (int m = 1; m <= 8; m <<= 1) {
            float ov = __shfl_xor(v, m, 64);
            int   ox = __shfl_xor(x, m, 64);
            if (ov < v || (ov == v && ox < x)) { v = ov; x = ox; }
        }
        if (lr == 0) {
            int row = wy * 64 + (e >> 2) * 16 + (lane >> 4) * 4 + (e & 3);
            cand_v[wx * TM + row] = v;
            cand_i[wx * TM + row] = x;
        }
    }
    __syncthreads();

    if (t < TM) {
        float v0 = cand_v[t];          int i0 = cand_i[t];
        #pragma unroll
        for (int q = 1; q < 4; ++q) {
            float v1 = cand_v[q * TM + t]; int i1 = cand_i[q * TM + t];
            if (v1 < v0 || (v1 == v0 && i1 < i0)) { v0 = v1; i0 = i1; }
        }
        unsigned sb = __float_as_uint(v0);
        sb = (sb & 0x80000000u) ? ~sb : (sb | 0x80000000u);
        packed[n0 + t] = ((unsigned long long)sb << 32) | (unsigned)i0;
    }
}

// ---------------------------------------------------------------------------
// Kernel 3: gather + straight-through + loss partials + histogram
// ---------------------------------------------------------------------------
__global__ void k_gather(const float* __restrict__ emb,
                         const float* __restrict__ ces,
                         const float* __restrict__ usage,
                         const unsigned long long* __restrict__ packed,
                         float* __restrict__ out_eq,
                         float* __restrict__ codes_f,
                         int* __restrict__ hist,
                         float* __restrict__ partials) {
    int t = threadIdx.x;
    int wave = t >> 6, lane = t & 63;
    int n = blockIdx.x * 4 + wave;
    int k = (int)(packed[n] & 0xFFFFFFFFull);
    float uc = fmaxf(usage[k], 1e-5f);
    int c = lane * 4;

    float4 e = *(const float4*)&emb[(size_t)n * CH + c];
    float4 v = *(const float4*)&ces[(size_t)k * CH + c];
    float ea[4] = {e.x, e.y, e.z, e.w};
    float va[4] = {v.x, v.y, v.z, v.w};
    float eqa[4];
    float p = 0.0f;
    #pragma unroll
    for (int q = 0; q < 4; ++q) {
        float cb = va[q] / uc;
        float eq = ea[q] + (cb - ea[q]);
        eqa[q] = eq;
        float d = eq - ea[q];
        p += d * d;
    }
    *(float4*)&out_eq[(size_t)n * CH + c] =
        (float4){eqa[0], eqa[1], eqa[2], eqa[3]};

    #pragma unroll
    for (int off = 32; off; off >>= 1) p += __shfl_down(p, off);
    __shared__ float ps[4];
    if (lane == 0) {
        ps[wave] = p;
        codes_f[n] = (float)k;
        atomicAdd(&hist[k], 1);
    }
    __syncthreads();
    if (t == 0) partials[blockIdx.x] = ps[0] + ps[1] + ps[2] + ps[3];
}

// ---------------------------------------------------------------------------
// Kernel 4: exclusive prefix sum over hist -> offs, cursor (1 block)
// ---------------------------------------------------------------------------
__global__ void k_scan(const int* __restrict__ hist,
                       int* __restrict__ offs,
                       int* __restrict__ cursor) {
    __shared__ int bs[256];
    int t = threadIdx.x;
    int base = t * 32;
    int loc[32];
    int s = 0;
    #pragma unroll
    for (int i = 0; i < 32; ++i) { loc[i] = s; s += hist[base + i]; }
    int mysum = s;
    bs[t] = s;
    __syncthreads();
    for (int off = 1; off < 256; off <<= 1) {
        int v = (t >= off) ? bs[t - off] : 0;
        __syncthreads();
        bs[t] += v;
        __syncthreads();
    }
    int excl = bs[t] - mysum;
    #pragma unroll
    for (int i = 0; i < 32; ++i) {
        int o = excl + loc[i];
        offs[base + i]   = o;
        cursor[base + i] = o;
    }
}

// ---------------------------------------------------------------------------
// Kernel 5: scatter token ids into code-sorted buckets
// ---------------------------------------------------------------------------
__global__ void k_scatter(const unsigned long long* __restrict__ packed,
                          int* __restrict__ cursor,
                          int* __restrict__ bucket) {
    int n = blockIdx.x * 256 + threadIdx.x;
    int k = (int)(packed[n] & 0xFFFFFFFFull);
    int pos = atomicAdd(&cursor[k], 1);
    bucket[pos] = n;
}

// ---------------------------------------------------------------------------
// Kernel 6: per-code EMA (one BLOCK per code: coalesced 1KB row loads,
// thread t owns channel t, no atomics, no wave-serial latency chain)
// ---------------------------------------------------------------------------
__global__ void k_ema(const float* __restrict__ emb,
                      const float* __restrict__ ces,
                      const float* __restrict__ usage,
                      const int* __restrict__ hist,
                      const int* __restrict__ offs,
                      const int* __restrict__ bucket,
                      float* __restrict__ out_ces,
                      float* __restrict__ out_usage) {
    const float s = 0.01f;
    const float oms = 1.0f - s;
    int k = blockIdx.x, t = threadIdx.x;
    int start = offs[k], cnt = hist[k];
    float sum = 0.0f;
    #pragma unroll 2
    for (int i = 0; i < cnt; ++i) {
        int n = bucket[start + i];            // block-uniform (scalar) load
        sum += emb[(size_t)n * CH + t];       // coalesced row
    }
    out_ces[(size_t)k * CH + t] = oms * ces[(size_t)k * CH + t] + s * sum;
    if (t == 0) out_usage[k] = oms * usage[k] + s * (float)cnt;
}

// ---------------------------------------------------------------------------
// Kernel 7: reduce loss partials, mean over 2^23 elements
// ---------------------------------------------------------------------------
__global__ void k_final(const float* __restrict__ partials,
                        float* __restrict__ out_loss) {
    int t = threadIdx.x;
    float p = 0.0f;
    for (int i = t; i < NT / 4; i += 256) p += partials[i];
    #pragma unroll
    for (int off = 32; off; off >>= 1) p += __shfl_down(p, off);
    __shared__ float ps[4];
    if ((t & 63) == 0) ps[t >> 6] = p;
    __syncthreads();
    if (t == 0)
        out_loss[0] = (ps[0] + ps[1] + ps[2] + ps[3]) * (1.0f / 8388608.0f);
}

extern "C" void kernel_launch(void* const* d_in, const int* in_sizes, int n_in,
                              void* d_out, int out_size, void* d_ws, size_t ws_size,
                              hipStream_t stream) {
    const float* emb   = (const float*)d_in[0];  // [32768, 256]
    const float* usage = (const float*)d_in[1];  // [8192]
    const float* ces   = (const float*)d_in[2];  // [8192, 256]

    float* out      = (float*)d_out;
    float* o_codes  = out;                       // 32768
    float* o_eq     = out + NT;                  // 8388608
    float* o_loss   = o_eq + (size_t)NT * CH;    // 1
    float* o_usage  = o_loss + 1;                // 8192
    float* o_ces    = o_usage + KC;              // 2097152

    unsigned long long* packed = (unsigned long long*)d_ws;   // NT u64
    float* cbsq     = (float*)(packed + NT);                  // KC
    float* partials = cbsq + KC;                              // NT/4
    int* hist   = (int*)(partials + NT / 4);                  // KC
    int* offs   = hist + KC;                                  // KC
    int* cursor = offs + KC;                                  // KC
    int* bucket = cursor + KC;                                // NT
    _Float16* eh  = (_Float16*)(bucket + NT);                 // NT*CH
    _Float16* el  = eh + (size_t)NT * CH;
    _Float16* cbh = el + (size_t)NT * CH;                     // KC*CH
    _Float16* cbl = cbh + (size_t)KC * CH;

    k_prep<<<KC + NT * CH / 1024, 256, 0, stream>>>(
        usage, ces, emb, cbh, cbl, cbsq, eh, el, hist);
    k_argmin<<<NT / TM, 512, 0, stream>>>(eh, el, cbh, cbl, cbsq, packed);
    k_gather<<<NT / 4, 256, 0, stream>>>(emb, ces, usage, packed, o_eq,
                                         o_codes, hist, partials);
    k_scan<<<1, 256, 0, stream>>>(hist, offs, cursor);
    k_scatter<<<NT / 256, 256, 0, stream>>>(packed, cursor, bucket);
    k_ema<<<KC, 256, 0, stream>>>(emb, ces, usage, hist, offs, bucket,
                                  o_ces, o_usage);
    k_final<<<1, 256, 0, stream>>>(partials, o_loss);
}